// Round 7
// baseline (152.287 us; speedup 1.0000x reference)
//
#include <hip/hip_runtime.h>
#include <math.h>

#define B_ 2
#define C_ 128
#define H_ 64
#define W_ 64
#define F_ 16
#define U_ 9
#define MD_ 4
#define UV_ 81
#define HW_ (H_*W_)
#define BF_ (B_*F_)

typedef float v2f __attribute__((ext_vector_type(2)));

// CDNA4 VOP3P packed fp32 — compiler won't select these from portable source
__device__ inline v2f pk_fma(v2f a, v2f b, v2f c) {
    v2f d;
    asm("v_pk_fma_f32 %0, %1, %2, %3" : "=v"(d) : "v"(a), "v"(b), "v"(c));
    return d;
}
__device__ inline v2f pk_mul(v2f a, v2f b) {
    v2f d;
    asm("v_pk_mul_f32 %0, %1, %2" : "=v"(d) : "v"(a), "v"(b));
    return d;
}

// cvol layout in workspace: cvol[uv][bf][pix], bf = b*F_+f, uv = u*9+v
//   (u = x-shift index, v = y-shift index; displacement du=u-4, dv=v-4)
// out0 layout: out0[bf][ch][pix], ch in {flowx, flowy, local_ent, global_ent}

// wave = one image row (64 lanes). Block = 4 waves = 4 rows.
// blockIdx.z = b*5 + g, g = u-group of 2 (group 4 has u=8 + dummy u=9, masked).
// c processed in pairs; packed halves carry (c, c+1).
#define NG_ 2
__global__ __launch_bounds__(256)
void cvol_kernel(const float* __restrict__ ref,
                 const float* __restrict__ tar,
                 const float* __restrict__ pw,
                 float* __restrict__ cvol) {
    const int t    = threadIdx.x;
    const int x    = t & 63;             // lane = pixel x
    const int y    = blockIdx.x * 4 + (t >> 6);   // wave = row
    const int vidx = blockIdx.y;         // 0..8  y-shift index
    const int z    = blockIdx.z;         // 0..9 = b*5 + g
    const int b    = z / 5;
    const int U0   = (z - b * 5) * NG_;  // 0,2,4,6,8
    const int dv   = vidx - MD_;
    const int ys   = y + dv;
    const bool rowv = ((unsigned)ys < (unsigned)H_);
    const int ysc  = rowv ? ys : 0;

    const float* rp = ref + (size_t)b * C_ * HW_ + y  * W_ + x;
    const float* tp = tar + (size_t)b * C_ * HW_ + ysc * W_ + x;

    bool xv[NG_];
#pragma unroll
    for (int i = 0; i < NG_; ++i) {
        int u = U0 + i;
        int du = u - MD_;
        xv[i] = (u < U_) && ((unsigned)(x + du) < (unsigned)W_);  // dummy u=9 masked
    }

    v2f acc[NG_][F_];                    // halves = (even c, odd c) partial sums
#pragma unroll
    for (int i = 0; i < NG_; ++i)
#pragma unroll
        for (int f = 0; f < F_; ++f) acc[i][f] = (v2f)0.f;

    const v2f tenth = {0.1f, 0.1f};

#pragma unroll 2
    for (int c = 0; c < C_; c += 2) {
        float r0 = rp[(size_t)(c + 0) * HW_];
        float r1 = rp[(size_t)(c + 1) * HW_];
        float t0 = tp[(size_t)(c + 0) * HW_];
        float t1 = tp[(size_t)(c + 1) * HW_];
        t0 = rowv ? t0 : 0.f;            // zero padding for OOB row
        t1 = rowv ? t1 : 0.f;
        v2f r2 = {r0, r1};

#pragma unroll
        for (int i = 0; i < NG_; ++i) {
            int du = U0 + i - MD_;
            float s0 = __shfl(t0, x + du);       // x-shift via ds_bpermute
            float s1 = __shfl(t1, x + du);
            v2f tv = {s0, s1};
            tv = xv[i] ? tv : (v2f)0.f;          // zero padding for OOB col
            v2f p = pk_mul(r2, tv);
            v2f q = pk_mul(p, tenth);
            p.x = fmaxf(p.x, q.x);               // leaky_relu(.,0.1)
            p.y = fmaxf(p.y, q.y);
#pragma unroll
            for (int f = 0; f < F_; ++f) {
                // contiguous pair {w[f,c], w[f,c+1]} -> one s_load_dwordx2
                v2f wv = *(const v2f*)(pw + f * C_ + c);
                acc[i][f] = pk_fma(wv, p, acc[i][f]);
            }
        }
    }

#pragma unroll
    for (int i = 0; i < NG_; ++i) {
        int u = U0 + i;
        if (u < U_) {                            // skip dummy plane
            int plane = u * U_ + vidx;           // uv = u*9 + v
            float* op = cvol + ((size_t)plane * BF_ + (size_t)b * F_) * HW_ + y * W_ + x;
#pragma unroll
            for (int f = 0; f < F_; ++f)
                op[(size_t)f * HW_] = acc[i][f].x + acc[i][f].y;  // fold parities
        }
    }
}

// 4 threads per pixel, each owning a chunk of the 81 uv-planes.
// chunks (ascending uv): j=0 -> [0,21), j=1 -> [21,41), j=2 -> [41,61), j=3 -> [61,81)
__global__ __launch_bounds__(256)
void flowreg_kernel(const float* __restrict__ cvol,
                    float* __restrict__ out0) {
    const int lane = threadIdx.x & 63;
    const int j    = threadIdx.x >> 6;              // 0..3 = uv chunk = wave id
    const int blk  = blockIdx.x;                    // over BF_*HW_/64 = 2048
    const int bf   = blk >> 6;                      // 64 blocks per bf
    const int pix  = (blk & 63) * 64 + lane;

    const float* cp = cvol + (size_t)bf * HW_ + pix;
    const size_t stride = (size_t)BF_ * HW_;

    const int start = (j == 0) ? 0 : (1 + j * 20);
    const int n     = (j == 0) ? 21 : 20;

    float v[21];
#pragma unroll 21
    for (int i = 0; i < n; ++i) v[i] = cp[(size_t)(start + i) * stride];

    // local argmax (ascending, strict > keeps first occurrence)
    float mv = v[0]; int bi = start;
#pragma unroll 21
    for (int i = 1; i < n; ++i) {
        if (v[i] > mv) { mv = v[i]; bi = start + i; }
    }

    __shared__ float smax[4][64];
    __shared__ int   sidx[4][64];
    smax[j][lane] = mv; sidx[j][lane] = bi;
    __syncthreads();

    // combine chunks ascending -> global first-occurrence argmax (all threads)
    float m = smax[0][lane]; int best = sidx[0][lane];
#pragma unroll
    for (int k = 1; k < 4; ++k) {
        float vv = smax[k][lane];
        if (vv > m) { m = vv; best = sidx[k][lane]; }
    }
    int ub = best / U_;           // x-shift index of argmax
    int vb = best - ub * U_;      // y-shift index

    float S = 0.f, A = 0.f, Sx = 0.f, Sy = 0.f, gS = 0.f, gA = 0.f;
#pragma unroll 21
    for (int i = 0; i < n; ++i) {
        int uv = start + i;
        float d = v[i] - m;
        float z = __expf(d);
        gS += z; gA = fmaf(z, d, gA);
        int u = uv / U_, vy = uv - u * U_;
        int duc = u - ub, dvc = vy - vb;
        bool msk = (duc <= 3) && (duc >= -3) && (dvc <= 3) && (dvc >= -3);
        float zm = msk ? z : 0.f;
        float dm = msk ? d : 0.f;
        S += zm;
        A = fmaf(zm, dm, A);
        Sx = fmaf(zm, (float)(u - MD_), Sx);
        Sy = fmaf(zm, (float)(vy - MD_), Sy);
    }

    __shared__ float sred[6][4][64];
    sred[0][j][lane] = S;  sred[1][j][lane] = A;
    sred[2][j][lane] = Sx; sred[3][j][lane] = Sy;
    sred[4][j][lane] = gS; sred[5][j][lane] = gA;
    __syncthreads();

    if (j == 0) {
        float r[6];
#pragma unroll
        for (int q = 0; q < 6; ++q) {
            float s = sred[q][0][lane];
#pragma unroll
            for (int k = 1; k < 4; ++k) s += sred[q][k][lane];
            r[q] = s;
        }
        float invS = 1.f / r[0];
        float outx = r[2] * invS;
        float outy = r[3] * invS;
        // sum p*log p = A/S - log S  (p = z/S, log p = d - log S)
        float lent = (logf(r[0]) - r[1] * invS) * (1.0f / logf(49.0f));
        float gent = (logf(r[4]) - r[5] / r[4]) * (1.0f / logf(81.0f));

        float* op = out0 + (size_t)bf * 4 * HW_ + pix;
        op[0 * HW_] = outx;
        op[1 * HW_] = outy;
        op[2 * HW_] = lent;
        op[3 * HW_] = gent;
    }
}

__global__ __launch_bounds__(256)
void warp_kernel(const float* __restrict__ tar,
                 const float* __restrict__ out0,
                 float* __restrict__ warped) {
    int tid = blockIdx.x * 256 + threadIdx.x;   // over B_*C_*HW_
    int pix = tid & (HW_ - 1);
    int bc  = tid >> 12;
    int b   = bc >> 7;                          // C_ = 128
    int x = pix & 63, y = pix >> 6;

    // flow = hypothesis f=0 of out0 for this b
    const float* fbase = out0 + (size_t)(b * F_) * 4 * HW_;
    float fx = fbase[pix];
    float fy = fbase[HW_ + pix];
    float px = (float)x + fx;
    float py = (float)y + fy;

    bool inb = (fabsf(2.0f * px / (float)(W_ - 1) - 1.0f) < 1.0f) &&
               (fabsf(2.0f * py / (float)(H_ - 1) - 1.0f) < 1.0f);

    float x0 = floorf(px), y0 = floorf(py);
    float wx = px - x0,    wy = py - y0;
    int x0i = (int)x0, y0i = (int)y0;

    const float* img = tar + (size_t)bc * HW_;

    auto tap = [&](int yi, int xi, float wgt) -> float {
        bool v = ((unsigned)xi < (unsigned)W_) && ((unsigned)yi < (unsigned)H_);
        int xc = xi < 0 ? 0 : (xi > W_ - 1 ? W_ - 1 : xi);
        int yc = yi < 0 ? 0 : (yi > H_ - 1 ? H_ - 1 : yi);
        float val = img[yc * W_ + xc];
        return val * (v ? wgt : 0.f);
    };

    float acc = tap(y0i,     x0i,     (1.f - wx) * (1.f - wy))
              + tap(y0i,     x0i + 1, wx * (1.f - wy))
              + tap(y0i + 1, x0i,     (1.f - wx) * wy)
              + tap(y0i + 1, x0i + 1, wx * wy);

    warped[tid] = inb ? acc : 0.f;
}

extern "C" void kernel_launch(void* const* d_in, const int* in_sizes, int n_in,
                              void* d_out, int out_size, void* d_ws, size_t ws_size,
                              hipStream_t stream) {
    const float* ref = (const float*)d_in[0];
    const float* tar = (const float*)d_in[1];
    const float* pw  = (const float*)d_in[2];
    float* out0 = (float*)d_out;                       // (B*F, 4, H, W) = 524288 floats
    float* out1 = out0 + (size_t)BF_ * 4 * HW_;        // (B, C, H, W)  = 2097152 floats
    float* cvol = (float*)d_ws;                        // 81*32*4096 floats = 42.5 MB

    dim3 gc(H_ / 4, U_, B_ * 5);                       // (row-quad, dv, b*5+ugroup)
    cvol_kernel<<<gc, 256, 0, stream>>>(ref, tar, pw, cvol);
    flowreg_kernel<<<(BF_ * HW_) / 64, 256, 0, stream>>>(cvol, out0);
    warp_kernel<<<(B_ * C_ * HW_) / 256, 256, 0, stream>>>(tar, out0, out1);
}

// Round 8
// 145.846 us; speedup vs baseline: 1.0442x; 1.0442x over previous
//
#include <hip/hip_runtime.h>
#include <math.h>

#define B_ 2
#define C_ 128
#define H_ 64
#define W_ 64
#define F_ 16
#define U_ 9
#define MD_ 4
#define UV_ 81
#define HW_ (H_*W_)
#define BF_ (B_*F_)

// cvol layout in workspace: cvol[uv][bf][pix], bf = b*F_+f, uv = u*9+v
//   (u = x-shift index, v = y-shift index; displacement du=u-4, dv=v-4)
// out0 layout: out0[bf][ch][pix], ch in {flowx, flowy, local_ent, global_ent}

// Block = 128 threads = 2 waves over the SAME row y and u-group, split by
// c-half (wave0: c<64, wave1: c>=64). Partials combined via LDS; wave0 stores.
// Grid (64 rows, 9 dv, 2b*3grp) = 3456 blocks = 6912 waves (~27/CU nominal).
#define NG_ 3
__global__ __launch_bounds__(128)
void cvol_kernel(const float* __restrict__ ref,
                 const float* __restrict__ tar,
                 const float* __restrict__ pw,
                 float* __restrict__ cvol) {
    const int t    = threadIdx.x;
    const int x    = t & 63;             // lane = pixel x
    const int wv   = t >> 6;             // 0/1 = c-half
    const int y    = blockIdx.x;         // row
    const int vidx = blockIdx.y;         // 0..8  y-shift index
    const int z    = blockIdx.z;         // 0..5 = b*3 + group
    const int b    = z / 3;
    const int U0   = (z - b * 3) * NG_;  // first x-shift index of this group
    const int dv   = vidx - MD_;
    const int ys   = y + dv;
    const bool rowv = ((unsigned)ys < (unsigned)H_);
    const int ysc  = rowv ? ys : 0;
    const int c0   = wv * 64;            // this wave's channel base

    const float* rp = ref + (size_t)b * C_ * HW_ + (size_t)c0 * HW_ + y  * W_ + x;
    const float* tp = tar + (size_t)b * C_ * HW_ + (size_t)c0 * HW_ + ysc * W_ + x;
    const float* wp = pw + c0;

    bool xv[NG_];
#pragma unroll
    for (int i = 0; i < NG_; ++i) {
        int du = U0 + i - MD_;
        xv[i] = ((unsigned)(x + du) < (unsigned)W_);
    }

    float acc[NG_][F_];
#pragma unroll
    for (int i = 0; i < NG_; ++i)
#pragma unroll
        for (int f = 0; f < F_; ++f) acc[i][f] = 0.f;

#pragma unroll 4
    for (int c = 0; c < 64; ++c) {       // this wave's 64 channels
        float rv = rp[(size_t)c * HW_];          // coalesced row load
        float tr = tp[(size_t)c * HW_];          // coalesced row load (clamped row)
        tr = rowv ? tr : 0.f;                    // zero padding for OOB row
#pragma unroll
        for (int i = 0; i < NG_; ++i) {
            int du = U0 + i - MD_;
            float tv = __shfl(tr, x + du);       // x-shift via ds_bpermute
            tv = xv[i] ? tv : 0.f;               // zero padding for OOB col
            float p = rv * tv;
            p = fmaxf(p, 0.1f * p);              // leaky_relu(.,0.1); lrelu(0)=0
#pragma unroll
            for (int f = 0; f < F_; ++f) {
                float w = wp[f * C_ + c];        // uniform -> scalar K$ load
                acc[i][f] = fmaf(w, p, acc[i][f]);
            }
        }
    }

    // combine c-halves: wave1 -> LDS, wave0 adds and stores
    __shared__ float part[NG_][F_][64];          // 12 KB, lane-major (2-way = free)
    if (wv == 1) {
#pragma unroll
        for (int i = 0; i < NG_; ++i)
#pragma unroll
            for (int f = 0; f < F_; ++f) part[i][f][x] = acc[i][f];
    }
    __syncthreads();
    if (wv == 0) {
#pragma unroll
        for (int i = 0; i < NG_; ++i) {
            int plane = (U0 + i) * U_ + vidx;    // uv = u*9 + v
            float* op = cvol + ((size_t)plane * BF_ + (size_t)b * F_) * HW_ + y * W_ + x;
#pragma unroll
            for (int f = 0; f < F_; ++f)
                op[(size_t)f * HW_] = acc[i][f] + part[i][f][x];
        }
    }
}

// 4 threads per pixel, each owning a chunk of the 81 uv-planes.
// chunks (ascending uv): j=0 -> [0,21), j=1 -> [21,41), j=2 -> [41,61), j=3 -> [61,81)
__global__ __launch_bounds__(256)
void flowreg_kernel(const float* __restrict__ cvol,
                    float* __restrict__ out0) {
    const int lane = threadIdx.x & 63;
    const int j    = threadIdx.x >> 6;              // 0..3 = uv chunk = wave id
    const int blk  = blockIdx.x;                    // over BF_*HW_/64 = 2048
    const int bf   = blk >> 6;                      // 64 blocks per bf
    const int pix  = (blk & 63) * 64 + lane;

    const float* cp = cvol + (size_t)bf * HW_ + pix;
    const size_t stride = (size_t)BF_ * HW_;

    const int start = (j == 0) ? 0 : (1 + j * 20);
    const int n     = (j == 0) ? 21 : 20;

    float v[21];
#pragma unroll 21
    for (int i = 0; i < n; ++i) v[i] = cp[(size_t)(start + i) * stride];

    // local argmax (ascending, strict > keeps first occurrence)
    float mv = v[0]; int bi = start;
#pragma unroll 21
    for (int i = 1; i < n; ++i) {
        if (v[i] > mv) { mv = v[i]; bi = start + i; }
    }

    __shared__ float smax[4][64];
    __shared__ int   sidx[4][64];
    smax[j][lane] = mv; sidx[j][lane] = bi;
    __syncthreads();

    // combine chunks ascending -> global first-occurrence argmax (all threads)
    float m = smax[0][lane]; int best = sidx[0][lane];
#pragma unroll
    for (int k = 1; k < 4; ++k) {
        float vv = smax[k][lane];
        if (vv > m) { m = vv; best = sidx[k][lane]; }
    }
    int ub = best / U_;           // x-shift index of argmax
    int vb = best - ub * U_;      // y-shift index

    float S = 0.f, A = 0.f, Sx = 0.f, Sy = 0.f, gS = 0.f, gA = 0.f;
#pragma unroll 21
    for (int i = 0; i < n; ++i) {
        int uv = start + i;
        float d = v[i] - m;
        float z = __expf(d);
        gS += z; gA = fmaf(z, d, gA);
        int u = uv / U_, vy = uv - u * U_;
        int duc = u - ub, dvc = vy - vb;
        bool msk = (duc <= 3) && (duc >= -3) && (dvc <= 3) && (dvc >= -3);
        float zm = msk ? z : 0.f;
        float dm = msk ? d : 0.f;
        S += zm;
        A = fmaf(zm, dm, A);
        Sx = fmaf(zm, (float)(u - MD_), Sx);
        Sy = fmaf(zm, (float)(vy - MD_), Sy);
    }

    __shared__ float sred[6][4][64];
    sred[0][j][lane] = S;  sred[1][j][lane] = A;
    sred[2][j][lane] = Sx; sred[3][j][lane] = Sy;
    sred[4][j][lane] = gS; sred[5][j][lane] = gA;
    __syncthreads();

    if (j == 0) {
        float r[6];
#pragma unroll
        for (int q = 0; q < 6; ++q) {
            float s = sred[q][0][lane];
#pragma unroll
            for (int k = 1; k < 4; ++k) s += sred[q][k][lane];
            r[q] = s;
        }
        float invS = 1.f / r[0];
        float outx = r[2] * invS;
        float outy = r[3] * invS;
        // sum p*log p = A/S - log S  (p = z/S, log p = d - log S)
        float lent = (logf(r[0]) - r[1] * invS) * (1.0f / logf(49.0f));
        float gent = (logf(r[4]) - r[5] / r[4]) * (1.0f / logf(81.0f));

        float* op = out0 + (size_t)bf * 4 * HW_ + pix;
        op[0 * HW_] = outx;
        op[1 * HW_] = outy;
        op[2 * HW_] = lent;
        op[3 * HW_] = gent;
    }
}

__global__ __launch_bounds__(256)
void warp_kernel(const float* __restrict__ tar,
                 const float* __restrict__ out0,
                 float* __restrict__ warped) {
    int tid = blockIdx.x * 256 + threadIdx.x;   // over B_*C_*HW_
    int pix = tid & (HW_ - 1);
    int bc  = tid >> 12;
    int b   = bc >> 7;                          // C_ = 128
    int x = pix & 63, y = pix >> 6;

    // flow = hypothesis f=0 of out0 for this b
    const float* fbase = out0 + (size_t)(b * F_) * 4 * HW_;
    float fx = fbase[pix];
    float fy = fbase[HW_ + pix];
    float px = (float)x + fx;
    float py = (float)y + fy;

    bool inb = (fabsf(2.0f * px / (float)(W_ - 1) - 1.0f) < 1.0f) &&
               (fabsf(2.0f * py / (float)(H_ - 1) - 1.0f) < 1.0f);

    float x0 = floorf(px), y0 = floorf(py);
    float wx = px - x0,    wy = py - y0;
    int x0i = (int)x0, y0i = (int)y0;

    const float* img = tar + (size_t)bc * HW_;

    auto tap = [&](int yi, int xi, float wgt) -> float {
        bool v = ((unsigned)xi < (unsigned)W_) && ((unsigned)yi < (unsigned)H_);
        int xc = xi < 0 ? 0 : (xi > W_ - 1 ? W_ - 1 : xi);
        int yc = yi < 0 ? 0 : (yi > H_ - 1 ? H_ - 1 : yi);
        float val = img[yc * W_ + xc];
        return val * (v ? wgt : 0.f);
    };

    float acc = tap(y0i,     x0i,     (1.f - wx) * (1.f - wy))
              + tap(y0i,     x0i + 1, wx * (1.f - wy))
              + tap(y0i + 1, x0i,     (1.f - wx) * wy)
              + tap(y0i + 1, x0i + 1, wx * wy);

    warped[tid] = inb ? acc : 0.f;
}

extern "C" void kernel_launch(void* const* d_in, const int* in_sizes, int n_in,
                              void* d_out, int out_size, void* d_ws, size_t ws_size,
                              hipStream_t stream) {
    const float* ref = (const float*)d_in[0];
    const float* tar = (const float*)d_in[1];
    const float* pw  = (const float*)d_in[2];
    float* out0 = (float*)d_out;                       // (B*F, 4, H, W) = 524288 floats
    float* out1 = out0 + (size_t)BF_ * 4 * HW_;        // (B, C, H, W)  = 2097152 floats
    float* cvol = (float*)d_ws;                        // 81*32*4096 floats = 42.5 MB

    dim3 gc(H_, U_, B_ * 3);                           // (row, dv, b*3+ugroup)
    cvol_kernel<<<gc, 128, 0, stream>>>(ref, tar, pw, cvol);
    flowreg_kernel<<<(BF_ * HW_) / 64, 256, 0, stream>>>(cvol, out0);
    warp_kernel<<<(B_ * C_ * HW_) / 256, 256, 0, stream>>>(tar, out0, out1);
}

// Round 10
// 129.878 us; speedup vs baseline: 1.1725x; 1.1229x over previous
//
#include <hip/hip_runtime.h>
#include <math.h>

#define B_ 2
#define C_ 128
#define H_ 64
#define W_ 64
#define F_ 16
#define U_ 9
#define MD_ 4
#define UV_ 81
#define HW_ (H_*W_)
#define BF_ (B_*F_)

// cvol layout in workspace (TRANSPOSED vs earlier rounds): cvol[bf][uv][pix],
//   bf = b*F_+f, uv = u*9+v (u = x-shift idx, v = y-shift idx; du=u-4, dv=v-4)
// out0 layout: out0[bf][ch][pix], ch in {flowx, flowy, local_ent, global_ent}

// R5-proven structure, 1-wave blocks. wave = one image row (64 lanes = 64 x).
// Grid (64 rows, 9 dv, 2b*3ugroups) = 3456 single-wave blocks (~13.5 waves/CU).
#define NG_ 3
__global__ __launch_bounds__(64)
void cvol_kernel(const float* __restrict__ ref,
                 const float* __restrict__ tar,
                 const float* __restrict__ pw,
                 float* __restrict__ cvol) {
    const int x    = threadIdx.x;        // lane = pixel x
    const int y    = blockIdx.x;         // row
    const int vidx = blockIdx.y;         // 0..8  y-shift index
    const int z    = blockIdx.z;         // 0..5 = b*3 + group
    const int b    = z / 3;
    const int U0   = (z - b * 3) * NG_;  // first x-shift index of this group
    const int dv   = vidx - MD_;
    const int ys   = y + dv;
    const bool rowv = ((unsigned)ys < (unsigned)H_);
    const int ysc  = rowv ? ys : 0;

    const float* rp = ref + (size_t)b * C_ * HW_ + y  * W_ + x;
    const float* tp = tar + (size_t)b * C_ * HW_ + ysc * W_ + x;

    bool xv[NG_];
#pragma unroll
    for (int i = 0; i < NG_; ++i) {
        int du = U0 + i - MD_;
        xv[i] = ((unsigned)(x + du) < (unsigned)W_);
    }

    float acc[NG_][F_];
#pragma unroll
    for (int i = 0; i < NG_; ++i)
#pragma unroll
        for (int f = 0; f < F_; ++f) acc[i][f] = 0.f;

#pragma unroll 4
    for (int c = 0; c < C_; ++c) {
        float rv = rp[(size_t)c * HW_];          // coalesced row load
        float tr = tp[(size_t)c * HW_];          // coalesced row load (clamped row)
        tr = rowv ? tr : 0.f;                    // zero padding for OOB row
#pragma unroll
        for (int i = 0; i < NG_; ++i) {
            int du = U0 + i - MD_;
            float tv = __shfl(tr, x + du);       // x-shift via ds_bpermute
            tv = xv[i] ? tv : 0.f;               // zero padding for OOB col
            float p = rv * tv;
            p = fmaxf(p, 0.1f * p);              // leaky_relu(.,0.1); lrelu(0)=0
#pragma unroll
            for (int f = 0; f < F_; ++f) {
                float w = pw[f * C_ + c];        // uniform -> scalar K$ load
                acc[i][f] = fmaf(w, p, acc[i][f]);
            }
        }
    }

#pragma unroll
    for (int i = 0; i < NG_; ++i) {
        int plane = (U0 + i) * U_ + vidx;        // uv = u*9 + v
#pragma unroll
        for (int f = 0; f < F_; ++f) {
            float* op = cvol + (((size_t)(b * F_ + f) * UV_) + plane) * HW_ + y * W_ + x;
            *op = acc[i][f];
        }
    }
}

// 4 threads per pixel, each owning a chunk of the 81 uv-planes.
// chunks (ascending uv): j=0 -> [0,21), j=1 -> [21,41), j=2 -> [41,61), j=3 -> [61,81)
// Transposed cvol: a block's reads span one contiguous 1.3 MB [uv][pix] slab.
__global__ __launch_bounds__(256)
void flowreg_kernel(const float* __restrict__ cvol,
                    float* __restrict__ out0) {
    const int lane = threadIdx.x & 63;
    const int j    = threadIdx.x >> 6;              // 0..3 = uv chunk = wave id
    const int blk  = blockIdx.x;                    // over BF_*HW_/64 = 2048
    const int bf   = blk >> 6;                      // 64 blocks per bf
    const int pix  = (blk & 63) * 64 + lane;

    const float* cp = cvol + (size_t)bf * UV_ * HW_ + pix;

    const int start = (j == 0) ? 0 : (1 + j * 20);
    const int n     = (j == 0) ? 21 : 20;

    float v[21];
#pragma unroll 21
    for (int i = 0; i < n; ++i) v[i] = cp[(size_t)(start + i) * HW_];

    // local argmax (ascending, strict > keeps first occurrence)
    float mv = v[0]; int bi = start;
#pragma unroll 21
    for (int i = 1; i < n; ++i) {
        if (v[i] > mv) { mv = v[i]; bi = start + i; }
    }

    __shared__ float smax[4][64];
    __shared__ int   sidx[4][64];
    smax[j][lane] = mv; sidx[j][lane] = bi;
    __syncthreads();

    // combine chunks ascending -> global first-occurrence argmax (all threads)
    float m = smax[0][lane]; int best = sidx[0][lane];
#pragma unroll
    for (int k = 1; k < 4; ++k) {
        float vv = smax[k][lane];
        if (vv > m) { m = vv; best = sidx[k][lane]; }
    }
    int ub = best / U_;           // x-shift index of argmax
    int vb = best - ub * U_;      // y-shift index

    float S = 0.f, A = 0.f, Sx = 0.f, Sy = 0.f, gS = 0.f, gA = 0.f;
#pragma unroll 21
    for (int i = 0; i < n; ++i) {
        int uv = start + i;
        float d = v[i] - m;
        float z = __expf(d);
        gS += z; gA = fmaf(z, d, gA);
        int u = uv / U_, vy = uv - u * U_;
        int duc = u - ub, dvc = vy - vb;
        bool msk = (duc <= 3) && (duc >= -3) && (dvc <= 3) && (dvc >= -3);
        float zm = msk ? z : 0.f;
        float dm = msk ? d : 0.f;
        S += zm;
        A = fmaf(zm, dm, A);
        Sx = fmaf(zm, (float)(u - MD_), Sx);
        Sy = fmaf(zm, (float)(vy - MD_), Sy);
    }

    __shared__ float sred[6][4][64];
    sred[0][j][lane] = S;  sred[1][j][lane] = A;
    sred[2][j][lane] = Sx; sred[3][j][lane] = Sy;
    sred[4][j][lane] = gS; sred[5][j][lane] = gA;
    __syncthreads();

    if (j == 0) {
        float r[6];
#pragma unroll
        for (int q = 0; q < 6; ++q) {
            float s = sred[q][0][lane];
#pragma unroll
            for (int k = 1; k < 4; ++k) s += sred[q][k][lane];
            r[q] = s;
        }
        float invS = 1.f / r[0];
        float outx = r[2] * invS;
        float outy = r[3] * invS;
        // sum p*log p = A/S - log S  (p = z/S, log p = d - log S)
        float lent = (logf(r[0]) - r[1] * invS) * (1.0f / logf(49.0f));
        float gent = (logf(r[4]) - r[5] / r[4]) * (1.0f / logf(81.0f));

        float* op = out0 + (size_t)bf * 4 * HW_ + pix;
        op[0 * HW_] = outx;
        op[1 * HW_] = outy;
        op[2 * HW_] = lent;
        op[3 * HW_] = gent;
    }
}

// 4 channels per thread: bilinear weights/indices computed once per 4 gathers.
__global__ __launch_bounds__(256)
void warp_kernel(const float* __restrict__ tar,
                 const float* __restrict__ out0,
                 float* __restrict__ warped) {
    int tid = blockIdx.x * 256 + threadIdx.x;   // over B_*(C_/4)*HW_ = 262144
    int pix = tid & (HW_ - 1);
    int t2  = tid >> 12;                        // b*(C_/4)+cg, 0..63
    int b   = t2 >> 5;                          // C_/4 = 32
    int cg  = t2 & 31;
    int x = pix & 63, y = pix >> 6;

    // flow = hypothesis f=0 of out0 for this b
    const float* fbase = out0 + (size_t)(b * F_) * 4 * HW_;
    float fx = fbase[pix];
    float fy = fbase[HW_ + pix];
    float px = (float)x + fx;
    float py = (float)y + fy;

    bool inb = (fabsf(2.0f * px / (float)(W_ - 1) - 1.0f) < 1.0f) &&
               (fabsf(2.0f * py / (float)(H_ - 1) - 1.0f) < 1.0f);

    float x0 = floorf(px), y0 = floorf(py);
    float wx = px - x0,    wy = py - y0;
    int x0i = (int)x0, y0i = (int)y0;

    const float* img = tar + ((size_t)b * C_ + cg * 4) * HW_;

    float acc[4] = {0.f, 0.f, 0.f, 0.f};
    auto tap = [&](int yi, int xi, float wgt) {
        bool v = ((unsigned)xi < (unsigned)W_) && ((unsigned)yi < (unsigned)H_);
        int xc = xi < 0 ? 0 : (xi > W_ - 1 ? W_ - 1 : xi);
        int yc = yi < 0 ? 0 : (yi > H_ - 1 ? H_ - 1 : yi);
        float wg = v ? wgt : 0.f;
        int lin = yc * W_ + xc;
#pragma unroll
        for (int k = 0; k < 4; ++k)
            acc[k] = fmaf(img[(size_t)k * HW_ + lin], wg, acc[k]);
    };

    tap(y0i,     x0i,     (1.f - wx) * (1.f - wy));
    tap(y0i,     x0i + 1, wx * (1.f - wy));
    tap(y0i + 1, x0i,     (1.f - wx) * wy);
    tap(y0i + 1, x0i + 1, wx * wy);

    float* op = warped + ((size_t)b * C_ + cg * 4) * HW_ + pix;
#pragma unroll
    for (int k = 0; k < 4; ++k)
        op[(size_t)k * HW_] = inb ? acc[k] : 0.f;
}

extern "C" void kernel_launch(void* const* d_in, const int* in_sizes, int n_in,
                              void* d_out, int out_size, void* d_ws, size_t ws_size,
                              hipStream_t stream) {
    const float* ref = (const float*)d_in[0];
    const float* tar = (const float*)d_in[1];
    const float* pw  = (const float*)d_in[2];
    float* out0 = (float*)d_out;                       // (B*F, 4, H, W) = 524288 floats
    float* out1 = out0 + (size_t)BF_ * 4 * HW_;        // (B, C, H, W)  = 2097152 floats
    float* cvol = (float*)d_ws;                        // 32*81*4096 floats = 42.5 MB

    dim3 gc(H_, U_, B_ * 3);                           // (row, dv, b*3+ugroup)
    cvol_kernel<<<gc, 64, 0, stream>>>(ref, tar, pw, cvol);
    flowreg_kernel<<<(BF_ * HW_) / 64, 256, 0, stream>>>(cvol, out0);
    warp_kernel<<<(B_ * (C_ / 4) * HW_) / 256, 256, 0, stream>>>(tar, out0, out1);
}